// Round 5
// baseline (2481.050 us; speedup 1.0000x reference)
//
#include <hip/hip_runtime.h>

#define NEGF (-1e30f)

typedef __attribute__((ext_vector_type(8))) short short8;
typedef __attribute__((ext_vector_type(4))) float float4v;

template <bool V> struct BC { static constexpr bool value = V; };

__device__ __forceinline__ short f2bf(float f) {
  union { float f; unsigned u; } v; v.f = f;
  unsigned r = v.u + 0x7fffu + ((v.u >> 16) & 1u);  // RNE truncate to bf16
  return (short)(r >> 16);
}
__device__ __forceinline__ float fastrcp(float x) { return __builtin_amdgcn_rcpf(x); }
__device__ __forceinline__ float clamp15(float x) { return __builtin_amdgcn_fmed3f(x, -15.0f, 15.0f); }

// ---------------------------------------------------------------------------
// prep: stage Wcat = [Wh1;Wh2] (256x640 f32) into bf16 MFMA B-fragment layout.
__global__ void prep_w_kernel(const float* __restrict__ Wh1, const float* __restrict__ Wh2,
                              short* __restrict__ wsW) {
  int t = blockIdx.x * 256 + threadIdx.x;   // 0..20479
  int lane = t & 63;
  int frag = t >> 6;                        // 0..319
  int nt = frag >> 3, kk = frag & 7;
  int n  = nt * 16 + (lane & 15);
  int kb = kk * 32 + (lane >> 4) * 8;
  short8 v;
#pragma unroll
  for (int j = 0; j < 8; ++j) {
    int k = kb + j;
    float w = (k < 128) ? Wh1[k * 640 + n] : Wh2[(k - 128) * 640 + n];
    v[j] = f2bf(w);
  }
  ((short8*)wsW)[frag * 64 + lane] = v;
}

// ---------------------------------------------------------------------------
// MDLSTM wavefront, ONE block per batch, 1024 threads = 16 waves (4/SIMD).
// Wave w: half = w>>3 (rows 0-15 / 16-31), g = w&7 (jj slice). All rows at
// the same diagonal d; ONE barrier per step; ZERO cross-block sync/atomics.
// vs R2 (same total per-CU work, proven 3.29us/step at 2 waves/SIMD): 4
// waves/SIMD interleave hides the MFMA->VALU->trans dependent-latency chains,
// and per-thread serial work halves (4 cells). Row-15 c hand-off crosses
// waves via double-buffered c_bnd LDS (barrier-separated, single writer).
// feat: 33-slot LDS ring, plain coalesced store flush (no atomics).
__global__ __launch_bounds__(1024)
void mdlstm_kernel(const float* __restrict__ X, const short* __restrict__ wsW,
                   const float* __restrict__ Wx, const float* __restrict__ bias,
                   float* __restrict__ feat) {
  __shared__ __align__(16) short h_buf[2][33][136];   // 17,952 B; row 0 = zero boundary
  __shared__ __align__(16) short wlds[14 * 4096];     // 114,688 B: g3 kk0-6, g4 kk0-6
  __shared__ float featbuf[33][132];                  // 17,424 B: column ring
  __shared__ float c_bnd[2][132];                     // 1,056 B: row15 c hand-off
  // LDS total 151,120 B (< proven 157,184)

  const int bat  = blockIdx.x;
  const int tid  = threadIdx.x;
  const int lane = tid & 63;
  const int w    = tid >> 6;          // 0..15
  const int half = w >> 3;            // 0: rows 0-15, 1: rows 16-31
  const int g    = w & 7;             // jj slice
  const int col  = lane & 15;
  const int quad = lane >> 4;
  const int jj   = g * 16 + col;

  for (int i = tid; i < 4488; i += 1024) ((int*)h_buf)[i] = 0;
  for (int i = tid; i < 33 * 132; i += 1024) ((float*)featbuf)[i] = 0.0f;
  if (tid < 264) ((float*)c_bnd)[tid] = 0.0f;
  {
    const uint4* s4 = (const uint4*)wsW;
    uint4* d4 = (uint4*)wlds;
    for (int i = tid; i < 14 * 512; i += 1024) {
      int c = i >> 9, off = i & 511;                  // chunk c, off = gg*64+ln
      int gg = off >> 6, ln = off & 63;
      int q  = (c < 7) ? 3 : 4;
      int kk = (c < 7) ? c : (c - 7);
      d4[i] = s4[(((q * 8 + gg) * 8) + kk) * 64 + ln];
    }
  }

  float wx[5], bg[5];
#pragma unroll
  for (int q = 0; q < 5; ++q) {
    wx[q] = Wx[q * 128 + jj];
    bg[q] = bias[q * 128 + jj];
  }
  float cp[4] = {0.f, 0.f, 0.f, 0.f};   // c-state: rows mbase..mbase+3

  const float* Xb = X + bat * 8192;      // X[b][t=256][f=32]
  float* fb = feat + bat * 32768;        // feat[b][w=256][jj=128]
  const short8* W8 = (const short8*)wsW;
  const short8* pW0 = W8 + ((0 * 8 + g) * 8) * 64 + lane;
  const short8* pW1 = W8 + ((1 * 8 + g) * 8) * 64 + lane;
  const short8* pW2 = W8 + ((2 * 8 + g) * 8) * 64 + lane;
  const short8 rb37 = W8[((3 * 8 + g) * 8 + 7) * 64 + lane];
  const short8 rb47 = W8[((4 * 8 + g) * 8 + 7) * 64 + lane];
  const short8* pL3 = (const short8*)wlds + g * 64 + lane;             // chunk kk   (kk<7)
  const short8* pL4 = (const short8*)wlds + 7 * 512 + g * 64 + lane;   // chunk 7+kk (kk<7)

  const int mbase  = half * 16 + quad * 4;             // global row of r=0
  const int rowoff = 1 + half * 16;                    // h_buf row base for A-frag
  const float* pX = Xb - 31 * mbase;                   // + d*32 per diag
  int sb = 0;                                          // d % 33
  __syncthreads();

  auto stepT = [&](int d, auto allv_) {
    constexpr bool ALLV = decltype(allv_)::value;
    const int rbuf = (d + 1) & 1, wbuf = d & 1;

    // Flush column w=d-32 (complete at end of step d-1). Slot (sb+1)%33 is
    // written by NO ring-writer during step d (they cover the other 32 slots).
    if (d >= 32 && tid < 128) {
      int fs = sb + 1; if (fs >= 33) fs = 0;
      float v = featbuf[fs][tid];
      featbuf[fs][tid] = 0.0f;
      fb[(d - 32) * 128 + tid] = v;                    // plain coalesced store
    }

    float4v acc[5];
#pragma unroll
    for (int q = 0; q < 5; ++q) acc[q] = (float4v){bg[q], bg[q], bg[q], bg[q]};
#pragma unroll
    for (int kk = 0; kk < 8; ++kk) {
      const int up = (kk >= 4) ? 1 : 0;                // kk<4: h_left; else h_up
      const int cc = (kk & 3) * 32 + quad * 8;
      short8 a0 = *(const short8*)&h_buf[rbuf][col + rowoff - up][cc];
      short8 b3 = (kk < 7) ? pL3[kk * 512] : rb37;
      acc[3] = __builtin_amdgcn_mfma_f32_16x16x32_bf16(a0, b3, acc[3], 0, 0, 0);
      short8 b4 = (kk < 7) ? pL4[kk * 512] : rb47;
      acc[4] = __builtin_amdgcn_mfma_f32_16x16x32_bf16(a0, b4, acc[4], 0, 0, 0);
      short8 b2 = pW2[kk * 64];
      acc[2] = __builtin_amdgcn_mfma_f32_16x16x32_bf16(a0, b2, acc[2], 0, 0, 0);
      short8 b0 = pW0[kk * 64];
      acc[0] = __builtin_amdgcn_mfma_f32_16x16x32_bf16(a0, b0, acc[0], 0, 0, 0);
      short8 b1 = pW1[kk * 64];
      acc[1] = __builtin_amdgcn_mfma_f32_16x16x32_bf16(a0, b1, acc[1], 0, 0, 0);
    }

    // c_up capture (all from PREVIOUS step's state, before any update):
    float t0 = __shfl_up(cp[3], 16);
    float c15 = c_bnd[rbuf][jj];                       // row-15 c of step d-1
    float cu[4];
    cu[0] = quad ? t0 : (half ? c15 : 0.0f);
    cu[1] = cp[0]; cu[2] = cp[1]; cu[3] = cp[2];
    const float* pXd = pX + d * 32;
    float xm[4];
#pragma unroll
    for (int r = 0; r < 4; ++r) {
      int ww = d - (mbase + r);
      if (ALLV || (ww >= 0 && ww < 256)) xm[r] = pXd[-31 * r];
    }
#pragma unroll
    for (int r = 0; r < 4; ++r) {
      const int m = mbase + r;
      const int ww = d - m;
      if (ALLV || (ww >= 0 && ww < 256)) {
        float c_up = cu[r];
        float c_l  = cp[r];
        float x    = xm[r];
        float zi = clamp15(fmaf(x, wx[0], acc[0][r]));
        float zg = clamp15(fmaf(x, wx[1], acc[1][r]));
        float z1 = clamp15(fmaf(x, wx[2], acc[2][r]));
        float z2 = clamp15(fmaf(x, wx[3], acc[3][r]));
        float zo = clamp15(fmaf(x, wx[4], acc[4][r]));
        float e1 = __expf(z1), e2 = __expf(z2), ei = __expf(zi), eg = __expf(2.0f * zg);
        float A1 = 1.0f + e1, A2 = 1.0f + e2, Ai = 1.0f + ei, G = 1.0f + eg;
        float P = Ai * G, Q = A1 * A2;
        float rD = fastrcp(P * Q);
        float c = (e1 * c_l * (A2 * P) + e2 * c_up * (A1 * P) + ei * (eg - 1.0f) * Q) * rD;
        float eo = __expf(-zo);
        float ec = __expf(2.0f * clamp15(c));
        float h = (ec - 1.0f) * fastrcp((1.0f + eo) * (ec + 1.0f));
        cp[r] = c;
        h_buf[wbuf][1 + m][jj] = f2bf(h);
        int s = sb - m; if (s < 0) s += 33;            // slot = w mod 33
        featbuf[s][jj] += h;                           // unique (slot,jj) writer
        if (!half && r == 3 && quad == 3)              // row-15 c -> half1 next step
          c_bnd[wbuf][jj] = c;
      }
    }
    __syncthreads();
  };

  BC<true> Tv; BC<false> Fv;
  for (int d = 0; d < 31; ++d)    { stepT(d, Fv); sb = (sb == 32) ? 0 : sb + 1; }
  for (int d = 31; d < 256; ++d)  { stepT(d, Tv); sb = (sb == 32) ? 0 : sb + 1; }
  for (int d = 256; d < 287; ++d) { stepT(d, Fv); sb = (sb == 32) ? 0 : sb + 1; }

  // Final column w=255 (complete after step 286; barrier at loop end).
  int fs = sb + 1; if (fs >= 33) fs = 0;               // sb=287%33=23 -> fs=24=255%33
  if (tid < 128) fb[255 * 128 + tid] = featbuf[fs][tid];
}

// ---------------------------------------------------------------------------
// logits = feat @ W_fc + b_fc, then log_softmax -> logp [32][256][101]
__global__ __launch_bounds__(256)
void logits_kernel(const float* __restrict__ feat, const float* __restrict__ Wfc,
                   const float* __restrict__ bfc, float* __restrict__ logp) {
  __shared__ float sW[128 * 101];
  __shared__ float sF[8][128];
  __shared__ float sL[8][104];
  __shared__ float sLse[8];
  const int tid = threadIdx.x;
  const int b  = blockIdx.x >> 5;
  const int t0 = (blockIdx.x & 31) * 8;

  for (int i = tid; i < 128 * 101; i += 256) sW[i] = Wfc[i];
  for (int i = tid; i < 8 * 128; i += 256)
    sF[i >> 7][i & 127] = feat[(b * 256 + t0 + (i >> 7)) * 128 + (i & 127)];
  __syncthreads();
  for (int idx = tid; idx < 8 * 101; idx += 256) {
    int tr = idx / 101, v = idx - tr * 101;
    float s = bfc[v];
#pragma unroll 4
    for (int k = 0; k < 128; ++k) s += sF[tr][k] * sW[k * 101 + v];
    sL[tr][v] = s;
  }
  __syncthreads();
  if (tid < 8) {
    float m = NEGF;
    for (int v = 0; v < 101; ++v) m = fmaxf(m, sL[tid][v]);
    float su = 0.0f;
    for (int v = 0; v < 101; ++v) su += __expf(sL[tid][v] - m);
    sLse[tid] = m + __logf(su);
  }
  __syncthreads();
  for (int idx = tid; idx < 8 * 101; idx += 256) {
    int tr = idx / 101, v = idx - tr * 101;
    logp[(b * 256 + t0 + tr) * 101 + v] = sL[tr][v] - sLse[tr];
  }
}

// ---------------------------------------------------------------------------
// CTC forward: one wave per batch. Lane l holds alpha[s=l]; lane 63 also s=64.
__global__ __launch_bounds__(64)
void ctc_kernel(const float* __restrict__ logp, const int* __restrict__ y,
                float* __restrict__ out) {
  const int b = blockIdx.x;
  const int l = threadIdx.x;
  const float* lpb = logp + b * 256 * 101;
  const int* yb = y + b * 32;
  int lab = (l & 1) ? yb[l >> 1] : 100;                 // ext[s]: odd->label, even->blank
  bool skip = (l & 1) && (l >= 3) && (yb[l >> 1] != yb[(l >> 1) - 1]);

  float a   = (l == 0) ? lpb[100] : ((l == 1) ? lpb[lab] : NEGF);
  float a64 = NEGF;                                      // alpha[64] (valid on lane 63)
  float pl[4], pb[4];
#pragma unroll
  for (int tt = 0; tt < 4; ++tt) {
    pl[tt] = lpb[(1 + tt) * 101 + lab];
    pb[tt] = lpb[(1 + tt) * 101 + 100];
  }
#pragma unroll 4
  for (int t = 1; t < 256; ++t) {
    const int s = (t - 1) & 3;
    float lpl = pl[s], lpbk = pb[s];
    if (t + 4 < 256) {                                   // refill slot with t+4
      pl[s] = lpb[(t + 4) * 101 + lab];
      pb[s] = lpb[(t + 4) * 101 + 100];
    }
    float am1 = __shfl_up(a, 1); if (l == 0) am1 = NEGF;
    float am2 = __shfl_up(a, 2); if (l < 2 || !skip) am2 = NEGF;
    float m3 = fmaxf(a, fmaxf(am1, am2));
    float na = m3 + __logf(__expf(a - m3) + __expf(am1 - m3) + __expf(am2 - m3)) + lpl;
    float m2 = fmaxf(a64, a);                            // s=64: lse(alpha64, alpha63)
    float na64 = m2 + __logf(__expf(a64 - m2) + __expf(a - m2)) + lpbk;
    a = na;
    a64 = na64;
  }
  float A63 = __shfl(a, 63);
  float A64 = __shfl(a64, 63);
  if (l == 0) {
    float m = fmaxf(A63, A64);
    out[b] = -(m + __logf(__expf(A63 - m) + __expf(A64 - m)));
  }
}

// ---------------------------------------------------------------------------
extern "C" void kernel_launch(void* const* d_in, const int* in_sizes, int n_in,
                              void* d_out, int out_size, void* d_ws, size_t ws_size,
                              hipStream_t stream) {
  const float* X   = (const float*)d_in[0];
  const int*   y   = (const int*)d_in[1];
  const float* Wx  = (const float*)d_in[2];
  const float* Wh1 = (const float*)d_in[3];
  const float* Wh2 = (const float*)d_in[4];
  const float* bi  = (const float*)d_in[5];
  const float* Wfc = (const float*)d_in[6];
  const float* bfc = (const float*)d_in[7];
  float* out = (float*)d_out;

  char* ws = (char*)d_ws;
  // Layout (max 0x778000 = 7.83 MB, proven footprint):
  //   wsW   0x000000 - 0x050000  (bf16 weight frags)
  //   logp  0x050000 - 0x378000  (written by logits)
  //   feat  0x378000 - 0x778000  (4 MB, plain stores from LDS ring flush)
  short* wsW  = (short*)(ws);
  float* logp = (float*)(ws + 0x50000);
  float* feat = (float*)(ws + 0x378000);

  prep_w_kernel<<<80, 256, 0, stream>>>(Wh1, Wh2, wsW);
  mdlstm_kernel<<<32, 1024, 0, stream>>>(X, wsW, Wx, bi, feat);
  logits_kernel<<<1024, 256, 0, stream>>>(feat, Wfc, bfc, logp);
  ctc_kernel<<<32, 64, 0, stream>>>(logp, y, out);
}

// Round 6
// 2464.605 us; speedup vs baseline: 1.0067x; 1.0067x over previous
//
#include <hip/hip_runtime.h>

#define NEGF (-1e30f)

typedef __attribute__((ext_vector_type(8))) short short8;
typedef __attribute__((ext_vector_type(4))) float float4v;

template <bool V> struct BC { static constexpr bool value = V; };

__device__ __forceinline__ short f2bf(float f) {
  union { float f; unsigned u; } v; v.f = f;
  unsigned r = v.u + 0x7fffu + ((v.u >> 16) & 1u);  // RNE truncate to bf16
  return (short)(r >> 16);
}
__device__ __forceinline__ float fastrcp(float x) { return __builtin_amdgcn_rcpf(x); }
__device__ __forceinline__ float clamp15(float x) { return __builtin_amdgcn_fmed3f(x, -15.0f, 15.0f); }

// ---------------------------------------------------------------------------
// prep: stage Wcat = [Wh1;Wh2] (256x640 f32) into bf16 MFMA B-fragment layout.
__global__ void prep_w_kernel(const float* __restrict__ Wh1, const float* __restrict__ Wh2,
                              short* __restrict__ wsW) {
  int t = blockIdx.x * 256 + threadIdx.x;   // 0..20479
  int lane = t & 63;
  int frag = t >> 6;                        // 0..319
  int nt = frag >> 3, kk = frag & 7;
  int n  = nt * 16 + (lane & 15);
  int kb = kk * 32 + (lane >> 4) * 8;
  short8 v;
#pragma unroll
  for (int j = 0; j < 8; ++j) {
    int k = kb + j;
    float w = (k < 128) ? Wh1[k * 640 + n] : Wh2[(k - 128) * 640 + n];
    v[j] = f2bf(w);
  }
  ((short8*)wsW)[frag * 64 + lane] = v;
}

// ---------------------------------------------------------------------------
// MDLSTM wavefront, ONE block per batch, 1024 threads = 16 waves (4/SIMD).
// Wave w: half = w>>3 (rows 0-15 / 16-31), g = w&7 (jj slice). All rows at
// the same diagonal d; ONE barrier per step; ZERO cross-block sync/atomics.
// R5 failed codegen-side: __launch_bounds__(1024) let LLVM target 8 waves/
// SIMD -> VGPR cap 64 -> spill to scratch (FETCH 8.8MB, 2.4ms). The (1024,4)
// form pins 1 block/CU (4 waves/SIMD), lifting the cap to 128 ~= the ~120
// this step body needs (R3 measured 120 for identical per-thread work).
// feat: 33-slot LDS ring, plain coalesced store flush (no atomics).
__global__ __launch_bounds__(1024, 4)
void mdlstm_kernel(const float* __restrict__ X, const short* __restrict__ wsW,
                   const float* __restrict__ Wx, const float* __restrict__ bias,
                   float* __restrict__ feat) {
  __shared__ __align__(16) short h_buf[2][33][136];   // 17,952 B; row 0 = zero boundary
  __shared__ __align__(16) short wlds[14 * 4096];     // 114,688 B: g3 kk0-6, g4 kk0-6
  __shared__ float featbuf[33][132];                  // 17,424 B: column ring
  __shared__ float c_bnd[2][132];                     // 1,056 B: row15 c hand-off
  // LDS total 151,120 B (< proven 157,184)

  const int bat  = blockIdx.x;
  const int tid  = threadIdx.x;
  const int lane = tid & 63;
  const int w    = tid >> 6;          // 0..15
  const int half = w >> 3;            // 0: rows 0-15, 1: rows 16-31
  const int g    = w & 7;             // jj slice
  const int col  = lane & 15;
  const int quad = lane >> 4;
  const int jj   = g * 16 + col;

  for (int i = tid; i < 4488; i += 1024) ((int*)h_buf)[i] = 0;
  for (int i = tid; i < 33 * 132; i += 1024) ((float*)featbuf)[i] = 0.0f;
  if (tid < 264) ((float*)c_bnd)[tid] = 0.0f;
  {
    const uint4* s4 = (const uint4*)wsW;
    uint4* d4 = (uint4*)wlds;
    for (int i = tid; i < 14 * 512; i += 1024) {
      int c = i >> 9, off = i & 511;                  // chunk c, off = gg*64+ln
      int gg = off >> 6, ln = off & 63;
      int q  = (c < 7) ? 3 : 4;
      int kk = (c < 7) ? c : (c - 7);
      d4[i] = s4[(((q * 8 + gg) * 8) + kk) * 64 + ln];
    }
  }

  float wx[5], bg[5];
#pragma unroll
  for (int q = 0; q < 5; ++q) {
    wx[q] = Wx[q * 128 + jj];
    bg[q] = bias[q * 128 + jj];
  }
  float cp[4] = {0.f, 0.f, 0.f, 0.f};   // c-state: rows mbase..mbase+3

  const float* Xb = X + bat * 8192;      // X[b][t=256][f=32]
  float* fb = feat + bat * 32768;        // feat[b][w=256][jj=128]
  const short8* W8 = (const short8*)wsW;
  const short8* pW0 = W8 + ((0 * 8 + g) * 8) * 64 + lane;
  const short8* pW1 = W8 + ((1 * 8 + g) * 8) * 64 + lane;
  const short8* pW2 = W8 + ((2 * 8 + g) * 8) * 64 + lane;
  const short8 rb37 = W8[((3 * 8 + g) * 8 + 7) * 64 + lane];
  const short8 rb47 = W8[((4 * 8 + g) * 8 + 7) * 64 + lane];
  const short8* pL3 = (const short8*)wlds + g * 64 + lane;             // chunk kk   (kk<7)
  const short8* pL4 = (const short8*)wlds + 7 * 512 + g * 64 + lane;   // chunk 7+kk (kk<7)

  const int mbase  = half * 16 + quad * 4;             // global row of r=0
  const int rowoff = 1 + half * 16;                    // h_buf row base for A-frag
  const float* pX = Xb - 31 * mbase;                   // + d*32 per diag
  int sb = 0;                                          // d % 33
  __syncthreads();

  auto stepT = [&](int d, auto allv_) {
    constexpr bool ALLV = decltype(allv_)::value;
    const int rbuf = (d + 1) & 1, wbuf = d & 1;

    // Flush column w=d-32 (complete at end of step d-1). Slot (sb+1)%33 is
    // written by NO ring-writer during step d (they cover the other 32 slots).
    if (d >= 32 && tid < 128) {
      int fs = sb + 1; if (fs >= 33) fs = 0;
      float v = featbuf[fs][tid];
      featbuf[fs][tid] = 0.0f;
      fb[(d - 32) * 128 + tid] = v;                    // plain coalesced store
    }

    float4v acc[5];
#pragma unroll
    for (int q = 0; q < 5; ++q) acc[q] = (float4v){bg[q], bg[q], bg[q], bg[q]};
#pragma unroll
    for (int kk = 0; kk < 8; ++kk) {
      const int up = (kk >= 4) ? 1 : 0;                // kk<4: h_left; else h_up
      const int cc = (kk & 3) * 32 + quad * 8;
      short8 a0 = *(const short8*)&h_buf[rbuf][col + rowoff - up][cc];
      short8 b3 = (kk < 7) ? pL3[kk * 512] : rb37;
      acc[3] = __builtin_amdgcn_mfma_f32_16x16x32_bf16(a0, b3, acc[3], 0, 0, 0);
      short8 b4 = (kk < 7) ? pL4[kk * 512] : rb47;
      acc[4] = __builtin_amdgcn_mfma_f32_16x16x32_bf16(a0, b4, acc[4], 0, 0, 0);
      short8 b2 = pW2[kk * 64];
      acc[2] = __builtin_amdgcn_mfma_f32_16x16x32_bf16(a0, b2, acc[2], 0, 0, 0);
      short8 b0 = pW0[kk * 64];
      acc[0] = __builtin_amdgcn_mfma_f32_16x16x32_bf16(a0, b0, acc[0], 0, 0, 0);
      short8 b1 = pW1[kk * 64];
      acc[1] = __builtin_amdgcn_mfma_f32_16x16x32_bf16(a0, b1, acc[1], 0, 0, 0);
    }

    // c_up capture (all from PREVIOUS step's state, before any update):
    float t0 = __shfl_up(cp[3], 16);
    float c15 = c_bnd[rbuf][jj];                       // row-15 c of step d-1
    float cu[4];
    cu[0] = quad ? t0 : (half ? c15 : 0.0f);
    cu[1] = cp[0]; cu[2] = cp[1]; cu[3] = cp[2];
    const float* pXd = pX + d * 32;
    float xm[4];
#pragma unroll
    for (int r = 0; r < 4; ++r) {
      int ww = d - (mbase + r);
      if (ALLV || (ww >= 0 && ww < 256)) xm[r] = pXd[-31 * r];
    }
#pragma unroll
    for (int r = 0; r < 4; ++r) {
      const int m = mbase + r;
      const int ww = d - m;
      if (ALLV || (ww >= 0 && ww < 256)) {
        float c_up = cu[r];
        float c_l  = cp[r];
        float x    = xm[r];
        float zi = clamp15(fmaf(x, wx[0], acc[0][r]));
        float zg = clamp15(fmaf(x, wx[1], acc[1][r]));
        float z1 = clamp15(fmaf(x, wx[2], acc[2][r]));
        float z2 = clamp15(fmaf(x, wx[3], acc[3][r]));
        float zo = clamp15(fmaf(x, wx[4], acc[4][r]));
        float e1 = __expf(z1), e2 = __expf(z2), ei = __expf(zi), eg = __expf(2.0f * zg);
        float A1 = 1.0f + e1, A2 = 1.0f + e2, Ai = 1.0f + ei, G = 1.0f + eg;
        float P = Ai * G, Q = A1 * A2;
        float rD = fastrcp(P * Q);
        float c = (e1 * c_l * (A2 * P) + e2 * c_up * (A1 * P) + ei * (eg - 1.0f) * Q) * rD;
        float eo = __expf(-zo);
        float ec = __expf(2.0f * clamp15(c));
        float h = (ec - 1.0f) * fastrcp((1.0f + eo) * (ec + 1.0f));
        cp[r] = c;
        h_buf[wbuf][1 + m][jj] = f2bf(h);
        int s = sb - m; if (s < 0) s += 33;            // slot = w mod 33
        featbuf[s][jj] += h;                           // unique (slot,jj) writer
        if (!half && r == 3 && quad == 3)              // row-15 c -> half1 next step
          c_bnd[wbuf][jj] = c;
      }
    }
    __syncthreads();
  };

  BC<true> Tv; BC<false> Fv;
  for (int d = 0; d < 31; ++d)    { stepT(d, Fv); sb = (sb == 32) ? 0 : sb + 1; }
  for (int d = 31; d < 256; ++d)  { stepT(d, Tv); sb = (sb == 32) ? 0 : sb + 1; }
  for (int d = 256; d < 287; ++d) { stepT(d, Fv); sb = (sb == 32) ? 0 : sb + 1; }

  // Final column w=255 (complete after step 286; barrier at loop end).
  int fs = sb + 1; if (fs >= 33) fs = 0;               // sb=287%33=23 -> fs=24=255%33
  if (tid < 128) fb[255 * 128 + tid] = featbuf[fs][tid];
}

// ---------------------------------------------------------------------------
// logits = feat @ W_fc + b_fc, then log_softmax -> logp [32][256][101]
__global__ __launch_bounds__(256)
void logits_kernel(const float* __restrict__ feat, const float* __restrict__ Wfc,
                   const float* __restrict__ bfc, float* __restrict__ logp) {
  __shared__ float sW[128 * 101];
  __shared__ float sF[8][128];
  __shared__ float sL[8][104];
  __shared__ float sLse[8];
  const int tid = threadIdx.x;
  const int b  = blockIdx.x >> 5;
  const int t0 = (blockIdx.x & 31) * 8;

  for (int i = tid; i < 128 * 101; i += 256) sW[i] = Wfc[i];
  for (int i = tid; i < 8 * 128; i += 256)
    sF[i >> 7][i & 127] = feat[(b * 256 + t0 + (i >> 7)) * 128 + (i & 127)];
  __syncthreads();
  for (int idx = tid; idx < 8 * 101; idx += 256) {
    int tr = idx / 101, v = idx - tr * 101;
    float s = bfc[v];
#pragma unroll 4
    for (int k = 0; k < 128; ++k) s += sF[tr][k] * sW[k * 101 + v];
    sL[tr][v] = s;
  }
  __syncthreads();
  if (tid < 8) {
    float m = NEGF;
    for (int v = 0; v < 101; ++v) m = fmaxf(m, sL[tid][v]);
    float su = 0.0f;
    for (int v = 0; v < 101; ++v) su += __expf(sL[tid][v] - m);
    sLse[tid] = m + __logf(su);
  }
  __syncthreads();
  for (int idx = tid; idx < 8 * 101; idx += 256) {
    int tr = idx / 101, v = idx - tr * 101;
    logp[(b * 256 + t0 + tr) * 101 + v] = sL[tr][v] - sLse[tr];
  }
}

// ---------------------------------------------------------------------------
// CTC forward: one wave per batch. Lane l holds alpha[s=l]; lane 63 also s=64.
__global__ __launch_bounds__(64)
void ctc_kernel(const float* __restrict__ logp, const int* __restrict__ y,
                float* __restrict__ out) {
  const int b = blockIdx.x;
  const int l = threadIdx.x;
  const float* lpb = logp + b * 256 * 101;
  const int* yb = y + b * 32;
  int lab = (l & 1) ? yb[l >> 1] : 100;                 // ext[s]: odd->label, even->blank
  bool skip = (l & 1) && (l >= 3) && (yb[l >> 1] != yb[(l >> 1) - 1]);

  float a   = (l == 0) ? lpb[100] : ((l == 1) ? lpb[lab] : NEGF);
  float a64 = NEGF;                                      // alpha[64] (valid on lane 63)
  float pl[4], pb[4];
#pragma unroll
  for (int tt = 0; tt < 4; ++tt) {
    pl[tt] = lpb[(1 + tt) * 101 + lab];
    pb[tt] = lpb[(1 + tt) * 101 + 100];
  }
#pragma unroll 4
  for (int t = 1; t < 256; ++t) {
    const int s = (t - 1) & 3;
    float lpl = pl[s], lpbk = pb[s];
    if (t + 4 < 256) {                                   // refill slot with t+4
      pl[s] = lpb[(t + 4) * 101 + lab];
      pb[s] = lpb[(t + 4) * 101 + 100];
    }
    float am1 = __shfl_up(a, 1); if (l == 0) am1 = NEGF;
    float am2 = __shfl_up(a, 2); if (l < 2 || !skip) am2 = NEGF;
    float m3 = fmaxf(a, fmaxf(am1, am2));
    float na = m3 + __logf(__expf(a - m3) + __expf(am1 - m3) + __expf(am2 - m3)) + lpl;
    float m2 = fmaxf(a64, a);                            // s=64: lse(alpha64, alpha63)
    float na64 = m2 + __logf(__expf(a64 - m2) + __expf(a - m2)) + lpbk;
    a = na;
    a64 = na64;
  }
  float A63 = __shfl(a, 63);
  float A64 = __shfl(a64, 63);
  if (l == 0) {
    float m = fmaxf(A63, A64);
    out[b] = -(m + __logf(__expf(A63 - m) + __expf(A64 - m)));
  }
}

// ---------------------------------------------------------------------------
extern "C" void kernel_launch(void* const* d_in, const int* in_sizes, int n_in,
                              void* d_out, int out_size, void* d_ws, size_t ws_size,
                              hipStream_t stream) {
  const float* X   = (const float*)d_in[0];
  const int*   y   = (const int*)d_in[1];
  const float* Wx  = (const float*)d_in[2];
  const float* Wh1 = (const float*)d_in[3];
  const float* Wh2 = (const float*)d_in[4];
  const float* bi  = (const float*)d_in[5];
  const float* Wfc = (const float*)d_in[6];
  const float* bfc = (const float*)d_in[7];
  float* out = (float*)d_out;

  char* ws = (char*)d_ws;
  // Layout (max 0x778000 = 7.83 MB, proven footprint):
  //   wsW   0x000000 - 0x050000  (bf16 weight frags)
  //   logp  0x050000 - 0x378000  (written by logits)
  //   feat  0x378000 - 0x778000  (4 MB, plain stores from LDS ring flush)
  short* wsW  = (short*)(ws);
  float* logp = (float*)(ws + 0x50000);
  float* feat = (float*)(ws + 0x378000);

  prep_w_kernel<<<80, 256, 0, stream>>>(Wh1, Wh2, wsW);
  mdlstm_kernel<<<32, 1024, 0, stream>>>(X, wsW, Wx, bi, feat);
  logits_kernel<<<1024, 256, 0, stream>>>(feat, Wfc, bfc, logp);
  ctc_kernel<<<32, 64, 0, stream>>>(logp, y, out);
}